// Round 6
// baseline (152.902 us; speedup 1.0000x reference)
//
#include <hip/hip_runtime.h>
#include <stdint.h>

// ScaledDotProductAttention: B=32, S=2048, D=64, fp32 in/out, temp=8.
// Swapped-operand flash attention, 32x32x16 bf16 MFMA, fp32 accum.
// KVBLK=128: 16 tiles, 4 independent QK^T accumulator chains.
// PV phase: ds_read_b64_tr_b16 in 8 groups of 4 with rolling counted
// lgkmcnt(8/../4/0) waits (T4) -- no full-drain stall; final wait doubles as
// pre-barrier drain. Double-buffered LDS, one raw s_barrier per tile.

#define BATCH 32
#define SEQ   2048
#define DIM   64
#define QBLK_WAVE 32
#define NWAVES 4
#define QBLK  (QBLK_WAVE*NWAVES)   // 128 q-rows per block
#define KVBLK 128
#define NT    (SEQ/KVBLK)          // 16 tiles
#define BUFSHORTS (KVBLK*DIM)      // 8192 shorts = 16 KiB per tensor per buffer

typedef __attribute__((ext_vector_type(8)))  __bf16   bf16x8;
typedef __attribute__((ext_vector_type(16))) float    f32x16;
typedef __attribute__((ext_vector_type(2)))  unsigned uint2v;
typedef __attribute__((ext_vector_type(4)))  unsigned uint4v;

static __device__ __forceinline__ unsigned cvt_pk(float lo, float hi) {
    unsigned r; asm("v_cvt_pk_bf16_f32 %0, %1, %2" : "=v"(r) : "v"(lo), "v"(hi)); return r;
}
static __device__ __forceinline__ float exp2v(float x) {
    float r; asm("v_exp_f32 %0, %1" : "=v"(r) : "v"(x)); return r;
}
// value held by lane^32 (both halves active)
static __device__ __forceinline__ float other_half(float v, int hi) {
    unsigned u = __builtin_bit_cast(unsigned, v);
    uint2v r = __builtin_amdgcn_permlane32_swap(u, u, false, false);
    return __builtin_bit_cast(float, hi ? r[0] : r[1]);
}

#define MFMA32(A, B, C) __builtin_amdgcn_mfma_f32_32x32x16_bf16((A), (B), (C), 0, 0, 0)
#define TRR(dst, OFFSTR) \
    asm volatile("ds_read_b64_tr_b16 %0, %1 offset:" OFFSTR : "=v"(dst) : "v"(trb))
#define TRG(KS, A, B, C, D) \
    do { TRR(ga[KS], A); TRR(gb[KS], B); TRR(gc[KS], C); TRR(gd[KS], D); } while (0)
#define WAITL(NSTR) \
    do { asm volatile("s_waitcnt lgkmcnt(" NSTR ")" ::: "memory"); \
         __builtin_amdgcn_sched_barrier(0); } while (0)
#define PVK(KS) \
    do { oacc0 = MFMA32(frag_of(ga[KS], gb[KS]), bfr[KS], oacc0); \
         oacc1 = MFMA32(frag_of(gc[KS], gd[KS]), bfr[KS], oacc1); } while (0)
#define MAX4(a,b,c,d) fmaxf(fmaxf((a),(b)), fmaxf((c),(d)))
#define SUM4(a,b,c,d) (((a)+(b)) + ((c)+(d)))

static __device__ __forceinline__ bf16x8 frag_of(uint2v r0, uint2v r1) {
    uint4v w = { r0[0], r0[1], r1[0], r1[1] };
    return __builtin_bit_cast(bf16x8, w);
}

__global__ __launch_bounds__(256, 2)
void attn_fwd_kernel(const float* __restrict__ q,
                     const float* __restrict__ k,
                     const float* __restrict__ v,
                     float* __restrict__ out)
{
    __shared__ unsigned short Ksh[2][BUFSHORTS];  // [key][d] bf16, 16B-chunk ^= (key&7)
    __shared__ unsigned short Vsh[2][BUFSHORTS];  // same layout

    // T1: chunked XCD swizzle — 512 blocks, 64 per XCD, contiguous batches per XCD
    const int id    = blockIdx.x;
    const int swz   = (id & 7) * ((SEQ / QBLK) * BATCH / 8) + (id >> 3);
    const int batch = swz >> 4;            // 16 qtiles per batch
    const int qtile = swz & 15;

    const int t    = threadIdx.x;
    const int lane = t & 63;
    const int wid  = t >> 6;
    const int hi   = lane >> 5;
    const int l31  = lane & 31;
    const int l7   = lane & 7;

    const size_t bbase = (size_t)batch * SEQ * DIM;
    const int q0w = qtile * QBLK + wid * QBLK_WAVE;

    // ---- Q B-frags (B[k=d][n=q]: n=lane&31, k=hi*8+j per 16-d block), scale 1/8*log2e
    bf16x8 qf[4];
    {
        const float sc = 0.125f * 1.44269504088896341f;
        const float* qp = q + bbase + (size_t)(q0w + l31) * DIM + hi * 8;
        #pragma unroll
        for (int dblk = 0; dblk < 4; ++dblk) {
            float4 f0 = *(const float4*)(qp + dblk * 16);
            float4 f1 = *(const float4*)(qp + dblk * 16 + 4);
            uint4v w = { cvt_pk(f0.x * sc, f0.y * sc), cvt_pk(f0.z * sc, f0.w * sc),
                         cvt_pk(f1.x * sc, f1.y * sc), cvt_pk(f1.z * sc, f1.w * sc) };
            qf[dblk] = __builtin_bit_cast(bf16x8, w);
        }
    }

    // ---- staging: thread t covers key-row t>>1 (0..127), d-half (t&1)*32
    const int srow = t >> 1, dh = t & 1;
    const float* kg = k + bbase + (size_t)srow * DIM + dh * 32;
    const float* vg = v + bbase + (size_t)srow * DIM + dh * 32;
    const int ch0s = ((4 * dh + 0) ^ (srow & 7)) * 8;  // swizzled 16B-chunk offsets (shorts)
    const int ch1s = ((4 * dh + 1) ^ (srow & 7)) * 8;
    const int ch2s = ((4 * dh + 2) ^ (srow & 7)) * 8;
    const int ch3s = ((4 * dh + 3) ^ (srow & 7)) * 8;

    // ---- tr_read per-lane base (buffer 0)
    const int bq = (l31 & 15) >> 2, ee = (lane >> 4) & 1, cc = lane & 3;
    const unsigned vb = (unsigned)(uintptr_t)&Vsh[0][0];
    const unsigned trbase = vb + (unsigned)((8 * hi + bq) * 128 +
                                            (((2 * ee + (cc >> 1)) ^ bq) * 16) + (cc & 1) * 8);

    f32x16 oacc0, oacc1;
    #pragma unroll
    for (int r = 0; r < 16; ++r) { oacc0[r] = 0.f; oacc1[r] = 0.f; }
    float m_run = 0.0f, l_run = 0.0f;   // defer-max: rarely updated

    // ---- prologue: stage tile 0 into buf0, issue tile-1 loads
    float4 rk[8], rv[8];
    #pragma unroll
    for (int i = 0; i < 8; ++i) {
        rk[i] = *(const float4*)(kg + i * 4);
        rv[i] = *(const float4*)(vg + i * 4);
    }
    {
        unsigned short* kst = &Ksh[0][srow * DIM];
        unsigned short* vst = &Vsh[0][srow * DIM];
        const int chs[4] = { ch0s, ch1s, ch2s, ch3s };
        #pragma unroll
        for (int i2 = 0; i2 < 4; ++i2) {
            uint4v kw = { cvt_pk(rk[2*i2].x, rk[2*i2].y), cvt_pk(rk[2*i2].z, rk[2*i2].w),
                          cvt_pk(rk[2*i2+1].x, rk[2*i2+1].y), cvt_pk(rk[2*i2+1].z, rk[2*i2+1].w) };
            uint4v vw = { cvt_pk(rv[2*i2].x, rv[2*i2].y), cvt_pk(rv[2*i2].z, rv[2*i2].w),
                          cvt_pk(rv[2*i2+1].x, rv[2*i2+1].y), cvt_pk(rv[2*i2+1].z, rv[2*i2+1].w) };
            *(uint4v*)&kst[chs[i2]] = kw;
            *(uint4v*)&vst[chs[i2]] = vw;
        }
    }
    #pragma unroll
    for (int i = 0; i < 8; ++i) {
        rk[i] = *(const float4*)(kg + KVBLK * DIM + i * 4);
        rv[i] = *(const float4*)(vg + KVBLK * DIM + i * 4);
    }
    asm volatile("s_waitcnt lgkmcnt(0)" ::: "memory");

    #pragma unroll 2
    for (int tile = 0; tile < NT; ++tile) {
        const int cur = tile & 1;
        __builtin_amdgcn_s_barrier();          // raw: no vmcnt drain
        __builtin_amdgcn_sched_barrier(0);

        const unsigned short* krow = &Ksh[cur][l31 * DIM];
        const unsigned trb = trbase + (unsigned)(cur * (2 * BUFSHORTS));

        // ---- S^T = K Q^T : 4 independent accumulator chains
        f32x16 s[4];
        #pragma unroll
        for (int kb = 0; kb < 4; ++kb)
            #pragma unroll
            for (int r = 0; r < 16; ++r) s[kb][r] = 0.f;
        __builtin_amdgcn_s_setprio(1);
        #pragma unroll
        for (int dblk = 0; dblk < 4; ++dblk) {
            int cofs = (((2 * dblk + hi) ^ l7) * 8);
            #pragma unroll
            for (int kb = 0; kb < 4; ++kb) {
                bf16x8 kf = *(const bf16x8*)&krow[kb * 32 * DIM + cofs];
                s[kb] = MFMA32(kf, qf[dblk], s[kb]);
            }
        }
        __builtin_amdgcn_s_setprio(0);

        // ---- stage next tile into other buffer (barrier-protected, drains in
        //      the first counted PV wait)
        if (tile + 1 < NT) {
            unsigned short* kst = &Ksh[cur ^ 1][srow * DIM];
            unsigned short* vst = &Vsh[cur ^ 1][srow * DIM];
            const int chs[4] = { ch0s, ch1s, ch2s, ch3s };
            #pragma unroll
            for (int i2 = 0; i2 < 4; ++i2) {
                uint4v kw = { cvt_pk(rk[2*i2].x, rk[2*i2].y), cvt_pk(rk[2*i2].z, rk[2*i2].w),
                              cvt_pk(rk[2*i2+1].x, rk[2*i2+1].y), cvt_pk(rk[2*i2+1].z, rk[2*i2+1].w) };
                uint4v vw = { cvt_pk(rv[2*i2].x, rv[2*i2].y), cvt_pk(rv[2*i2].z, rv[2*i2].w),
                              cvt_pk(rv[2*i2+1].x, rv[2*i2+1].y), cvt_pk(rv[2*i2+1].z, rv[2*i2+1].w) };
                *(uint4v*)&kst[chs[i2]] = kw;
                *(uint4v*)&vst[chs[i2]] = vw;
            }
        }
        __builtin_amdgcn_sched_barrier(0);

        // ---- early tr_read groups (latency hides under softmax)
        uint2v ga[8], gb[8], gc[8], gd[8];
        TRG(0, "0",    "576",  "64",   "512");
        TRG(1, "2048", "2624", "2112", "2560");

        // ---- softmax: tree max, defer-max check, exp, tree sum
        {
            float mx[16];
            #pragma unroll
            for (int r = 0; r < 16; ++r)
                mx[r] = MAX4(s[0][r], s[1][r], s[2][r], s[3][r]);
            float p0 = MAX4(mx[0],  mx[1],  mx[2],  mx[3]);
            float p1 = MAX4(mx[4],  mx[5],  mx[6],  mx[7]);
            float p2 = MAX4(mx[8],  mx[9],  mx[10], mx[11]);
            float p3 = MAX4(mx[12], mx[13], mx[14], mx[15]);
            float pmax = MAX4(p0, p1, p2, p3);
            pmax = fmaxf(pmax, other_half(pmax, hi));
            if (!__all(pmax - m_run <= 12.0f)) {    // T13: almost never taken
                float mn    = fmaxf(m_run, pmax);
                float alpha = exp2v(m_run - mn);
                m_run = mn;
                l_run *= alpha;
                #pragma unroll
                for (int r = 0; r < 16; ++r) { oacc0[r] *= alpha; oacc1[r] *= alpha; }
            }
        }
        #pragma unroll
        for (int kb = 0; kb < 4; ++kb)
            #pragma unroll
            for (int r = 0; r < 16; ++r) s[kb][r] = exp2v(s[kb][r] - m_run);
        {
            float sx[16];
            #pragma unroll
            for (int r = 0; r < 16; ++r)
                sx[r] = SUM4(s[0][r], s[1][r], s[2][r], s[3][r]);
            float q0s = SUM4(sx[0],  sx[1],  sx[2],  sx[3]);
            float q1s = SUM4(sx[4],  sx[5],  sx[6],  sx[7]);
            float q2s = SUM4(sx[8],  sx[9],  sx[10], sx[11]);
            float q3s = SUM4(sx[12], sx[13], sx[14], sx[15]);
            float rs = SUM4(q0s, q1s, q2s, q3s);
            rs += other_half(rs, hi);
            l_run += rs;
        }

        // ---- P^T B-frags via cvt_pk + permlane32_swap (T12): 2 frags per kb
        bf16x8 bfr[8];
        #pragma unroll
        for (int kb = 0; kb < 4; ++kb) {
            uint2v x1 = __builtin_amdgcn_permlane32_swap(cvt_pk(s[kb][0],  s[kb][1]),
                                                         cvt_pk(s[kb][4],  s[kb][5]),  false, false);
            uint2v x2 = __builtin_amdgcn_permlane32_swap(cvt_pk(s[kb][2],  s[kb][3]),
                                                         cvt_pk(s[kb][6],  s[kb][7]),  false, false);
            uint4v w1 = { x1[0], x2[0], x1[1], x2[1] };
            bfr[2*kb] = __builtin_bit_cast(bf16x8, w1);
            uint2v y1 = __builtin_amdgcn_permlane32_swap(cvt_pk(s[kb][8],  s[kb][9]),
                                                         cvt_pk(s[kb][12], s[kb][13]), false, false);
            uint2v y2 = __builtin_amdgcn_permlane32_swap(cvt_pk(s[kb][10], s[kb][11]),
                                                         cvt_pk(s[kb][14], s[kb][15]), false, false);
            uint4v w2 = { y1[0], y2[0], y1[1], y2[1] };
            bfr[2*kb+1] = __builtin_bit_cast(bf16x8, w2);
        }

        // ---- PV: rolling 3-group tr_read pipeline, counted waits (T4).
        // DS queue (in-order): [stage writes][G0][G1][G2]...; lgkmcnt(8) leaves
        // exactly the two newest groups -> G(ks) + all writes complete.
        __builtin_amdgcn_s_setprio(1);
        TRG(2, "4096",  "4672",  "4160",  "4608");
        WAITL("8");  PVK(0);  TRG(3, "6144",  "6720",  "6208",  "6656");
        WAITL("8");  PVK(1);  TRG(4, "8192",  "8768",  "8256",  "8704");
        WAITL("8");  PVK(2);  TRG(5, "10240", "10816", "10304", "10752");
        WAITL("8");  PVK(3);  TRG(6, "12288", "12864", "12352", "12800");
        WAITL("8");  PVK(4);  TRG(7, "14336", "14912", "14400", "14848");
        WAITL("8");  PVK(5);
        WAITL("4");  PVK(6);
        WAITL("0");  PVK(7);   // final wait doubles as pre-barrier DS drain
        __builtin_amdgcn_s_setprio(0);

        // ---- issue tile+2 global loads (consumed after next barrier + QK^T)
        if (tile + 2 < NT) {
            const float* kp = kg + (size_t)(tile + 2) * KVBLK * DIM;
            const float* vp = vg + (size_t)(tile + 2) * KVBLK * DIM;
            #pragma unroll
            for (int i = 0; i < 8; ++i) {
                rk[i] = *(const float4*)(kp + i * 4);
                rv[i] = *(const float4*)(vp + i * 4);
            }
        }
    }

    // ---- epilogue: O^T regs (d = mblk*32 + crow(r,hi), q = l31), normalize, store
    float invl = 1.0f / l_run;
    float* op = out + bbase + (size_t)(q0w + l31) * DIM + 4 * hi;
    #pragma unroll
    for (int rq = 0; rq < 4; ++rq) {
        float4 o0 = { oacc0[4 * rq] * invl, oacc0[4 * rq + 1] * invl,
                      oacc0[4 * rq + 2] * invl, oacc0[4 * rq + 3] * invl };
        float4 o1 = { oacc1[4 * rq] * invl, oacc1[4 * rq + 1] * invl,
                      oacc1[4 * rq + 2] * invl, oacc1[4 * rq + 3] * invl };
        *(float4*)(op + 8 * rq)      = o0;
        *(float4*)(op + 32 + 8 * rq) = o1;
    }
}

extern "C" void kernel_launch(void* const* d_in, const int* in_sizes, int n_in,
                              void* d_out, int out_size, void* d_ws, size_t ws_size,
                              hipStream_t stream) {
    const float* q = (const float*)d_in[0];
    const float* k = (const float*)d_in[1];
    const float* v = (const float*)d_in[2];
    float* out = (float*)d_out;
    dim3 grid((SEQ / QBLK) * BATCH);   // 512
    dim3 block(256);
    hipLaunchKernelGGL(attn_fwd_kernel, grid, block, 0, stream, q, k, v, out);
}

// Round 7
// 131.156 us; speedup vs baseline: 1.1658x; 1.1658x over previous
//
#include <hip/hip_runtime.h>
#include <stdint.h>

// ScaledDotProductAttention: B=32, S=2048, D=64, fp32 in/out, temp=8.
// Swapped-operand flash attention, 32x32x16 bf16 MFMA, fp32 accum.
// Round-3 structure (KVBLK=64, one raw s_barrier/tile, dbuf LDS) + VALU diet:
//  - S/Q fragments pinned to VGPRs (avoid AGPR accvgpr-move tax)
//  - scalar-cast bf16 packing (compiler emits v_cvt_pk_bf16_f32; m240)
//  - v_max3_f32 max tree, m==0 fast-path exp (defer-max never fires for N(0,1))

#define BATCH 32
#define SEQ   2048
#define DIM   64
#define QBLK_WAVE 32
#define NWAVES 4
#define QBLK  (QBLK_WAVE*NWAVES)   // 128 q-rows per block
#define KVBLK 64
#define NT    (SEQ/KVBLK)          // 32 tiles
#define BUFSHORTS (KVBLK*DIM)      // 4096 shorts = 8 KiB per tensor per buffer

typedef __attribute__((ext_vector_type(8)))  __bf16   bf16x8;
typedef __attribute__((ext_vector_type(2)))  __bf16   bf16x2;
typedef __attribute__((ext_vector_type(16))) float    f32x16;
typedef __attribute__((ext_vector_type(2)))  unsigned uint2v;
typedef __attribute__((ext_vector_type(4)))  unsigned uint4v;

// pack two f32 -> one u32 of 2xbf16 via scalar casts (compiler fuses to
// v_cvt_pk_bf16_f32; inline-asm version measured -37%, m240)
static __device__ __forceinline__ unsigned pk(float lo, float hi) {
    bf16x2 p; p[0] = (__bf16)lo; p[1] = (__bf16)hi;
    return __builtin_bit_cast(unsigned, p);
}
static __device__ __forceinline__ float exp2v(float x) {
    float r; asm("v_exp_f32 %0, %1" : "=v"(r) : "v"(x)); return r;
}
static __device__ __forceinline__ float max3(float a, float b, float c) {
    float d; asm("v_max3_f32 %0, %1, %2, %3" : "=v"(d) : "v"(a), "v"(b), "v"(c));
    return d;
}
// value held by lane^32 (both halves active)
static __device__ __forceinline__ float other_half(float v, int hi) {
    unsigned u = __builtin_bit_cast(unsigned, v);
    uint2v r = __builtin_amdgcn_permlane32_swap(u, u, false, false);
    return __builtin_bit_cast(float, hi ? r[0] : r[1]);
}

#define MFMA32(A, B, C) __builtin_amdgcn_mfma_f32_32x32x16_bf16((A), (B), (C), 0, 0, 0)
#define TRR(dst, OFFSTR) \
    asm volatile("ds_read_b64_tr_b16 %0, %1 offset:" OFFSTR : "=v"(dst) : "v"(trb))
#define SUM4(a,b,c,d) (((a)+(b)) + ((c)+(d)))

static __device__ __forceinline__ bf16x8 frag_of(uint2v r0, uint2v r1) {
    uint4v w = { r0[0], r0[1], r1[0], r1[1] };
    return __builtin_bit_cast(bf16x8, w);
}

__global__ __launch_bounds__(256, 2)
void attn_fwd_kernel(const float* __restrict__ q,
                     const float* __restrict__ k,
                     const float* __restrict__ v,
                     float* __restrict__ out)
{
    __shared__ unsigned short Ksh[2][BUFSHORTS];  // [key][d] bf16, 16B-chunk ^= (key&7)
    __shared__ unsigned short Vsh[2][BUFSHORTS];  // same layout

    // T1: chunked XCD swizzle — 512 blocks, 64 per XCD, contiguous batches per XCD
    const int id    = blockIdx.x;
    const int swz   = (id & 7) * ((SEQ / QBLK) * BATCH / 8) + (id >> 3);
    const int batch = swz >> 4;            // 16 qtiles per batch
    const int qtile = swz & 15;

    const int t    = threadIdx.x;
    const int lane = t & 63;
    const int wid  = t >> 6;
    const int hi   = lane >> 5;
    const int l31  = lane & 31;
    const int l7   = lane & 7;

    const size_t bbase = (size_t)batch * SEQ * DIM;
    const int q0w = qtile * QBLK + wid * QBLK_WAVE;

    // ---- Q B-frags (B[k=d][n=q]: n=lane&31, k=hi*8+j per 16-d block), scale 1/8*log2e
    bf16x8 qf[4];
    {
        const float sc = 0.125f * 1.44269504088896341f;
        const float* qp = q + bbase + (size_t)(q0w + l31) * DIM + hi * 8;
        #pragma unroll
        for (int dblk = 0; dblk < 4; ++dblk) {
            float4 f0 = *(const float4*)(qp + dblk * 16);
            float4 f1 = *(const float4*)(qp + dblk * 16 + 4);
            uint4v w = { pk(f0.x * sc, f0.y * sc), pk(f0.z * sc, f0.w * sc),
                         pk(f1.x * sc, f1.y * sc), pk(f1.z * sc, f1.w * sc) };
            qf[dblk] = __builtin_bit_cast(bf16x8, w);
        }
    }
    // pin Q fragments to VGPRs (MFMA reads them every tile; AGPR would cost moves)
    asm("" : "+v"(qf[0]), "+v"(qf[1]), "+v"(qf[2]), "+v"(qf[3]));

    // ---- staging: thread t covers key-row t>>2, d-range (t&3)*16 (coalesced)
    const int srow = t >> 2, sq = t & 3;
    const float* kg = k + bbase + (size_t)srow * DIM + sq * 16;
    const float* vg = v + bbase + (size_t)srow * DIM + sq * 16;
    const int ch0 = ((2 * sq)     ^ (srow & 7)) * 8;   // swizzled 16B-chunk offsets
    const int ch1 = ((2 * sq + 1) ^ (srow & 7)) * 8;

    // ---- tr_read per-lane base (buffer 0)
    const int bq = (l31 & 15) >> 2, ee = (lane >> 4) & 1, cc = lane & 3;
    const unsigned vb = (unsigned)(uintptr_t)&Vsh[0][0];
    const unsigned trbase = vb + (unsigned)((8 * hi + bq) * 128 +
                                            (((2 * ee + (cc >> 1)) ^ bq) * 16) + (cc & 1) * 8);

    f32x16 oacc0, oacc1;
    #pragma unroll
    for (int r = 0; r < 16; ++r) { oacc0[r] = 0.f; oacc1[r] = 0.f; }
    float m_run = 0.0f, l_run = 0.0f;   // defer-max: m stays 0 on the fast path

    // ---- prologue: stage tile 0 into buf0, issue tile-1 loads
    float4 rk[4], rv[4];
    #pragma unroll
    for (int i = 0; i < 4; ++i) {
        rk[i] = *(const float4*)(kg + i * 4);
        rv[i] = *(const float4*)(vg + i * 4);
    }
    {
        uint4v kw0 = { pk(rk[0].x, rk[0].y), pk(rk[0].z, rk[0].w),
                       pk(rk[1].x, rk[1].y), pk(rk[1].z, rk[1].w) };
        uint4v kw1 = { pk(rk[2].x, rk[2].y), pk(rk[2].z, rk[2].w),
                       pk(rk[3].x, rk[3].y), pk(rk[3].z, rk[3].w) };
        uint4v vw0 = { pk(rv[0].x, rv[0].y), pk(rv[0].z, rv[0].w),
                       pk(rv[1].x, rv[1].y), pk(rv[1].z, rv[1].w) };
        uint4v vw1 = { pk(rv[2].x, rv[2].y), pk(rv[2].z, rv[2].w),
                       pk(rv[3].x, rv[3].y), pk(rv[3].z, rv[3].w) };
        *(uint4v*)&Ksh[0][srow * DIM + ch0] = kw0;
        *(uint4v*)&Ksh[0][srow * DIM + ch1] = kw1;
        *(uint4v*)&Vsh[0][srow * DIM + ch0] = vw0;
        *(uint4v*)&Vsh[0][srow * DIM + ch1] = vw1;
    }
    #pragma unroll
    for (int i = 0; i < 4; ++i) {
        rk[i] = *(const float4*)(kg + KVBLK * DIM + i * 4);
        rv[i] = *(const float4*)(vg + KVBLK * DIM + i * 4);
    }
    asm volatile("s_waitcnt lgkmcnt(0)" ::: "memory");

    #pragma unroll 2
    for (int tile = 0; tile < NT; ++tile) {
        const int cur = tile & 1;
        __builtin_amdgcn_s_barrier();          // raw: no vmcnt drain
        __builtin_amdgcn_sched_barrier(0);

        const unsigned short* krow = &Ksh[cur][l31 * DIM];
        const unsigned trb = trbase + (unsigned)(cur * (2 * BUFSHORTS));

        // ---- S^T = K Q^T
        f32x16 s0, s1;
        #pragma unroll
        for (int r = 0; r < 16; ++r) { s0[r] = 0.f; s1[r] = 0.f; }
        __builtin_amdgcn_s_setprio(1);
        #pragma unroll
        for (int dblk = 0; dblk < 4; ++dblk) {
            int cofs = (((2 * dblk + hi) ^ l7) * 8);
            bf16x8 kf0 = *(const bf16x8*)&krow[cofs];
            bf16x8 kf1 = *(const bf16x8*)&krow[32 * DIM + cofs];
            s0 = MFMA32(kf0, qf[dblk], s0);
            s1 = MFMA32(kf1, qf[dblk], s1);
        }
        __builtin_amdgcn_s_setprio(0);
        // pin S to VGPRs: softmax reads/writes every element; AGPR residency
        // would add v_accvgpr moves per access (round-3/6 VALU anomaly theory)
        asm("" : "+v"(s0), "+v"(s1));

        // ---- stage next tile into other buffer early (drains during softmax)
        if (tile + 1 < NT) {
            unsigned short* kst = &Ksh[cur ^ 1][srow * DIM];
            unsigned short* vst = &Vsh[cur ^ 1][srow * DIM];
            uint4v kw0 = { pk(rk[0].x, rk[0].y), pk(rk[0].z, rk[0].w),
                           pk(rk[1].x, rk[1].y), pk(rk[1].z, rk[1].w) };
            uint4v kw1 = { pk(rk[2].x, rk[2].y), pk(rk[2].z, rk[2].w),
                           pk(rk[3].x, rk[3].y), pk(rk[3].z, rk[3].w) };
            uint4v vw0 = { pk(rv[0].x, rv[0].y), pk(rv[0].z, rv[0].w),
                           pk(rv[1].x, rv[1].y), pk(rv[1].z, rv[1].w) };
            uint4v vw1 = { pk(rv[2].x, rv[2].y), pk(rv[2].z, rv[2].w),
                           pk(rv[3].x, rv[3].y), pk(rv[3].z, rv[3].w) };
            *(uint4v*)&kst[ch0] = kw0;
            *(uint4v*)&kst[ch1] = kw1;
            *(uint4v*)&vst[ch0] = vw0;
            *(uint4v*)&vst[ch1] = vw1;
        }

        // ---- issue V^T tr_reads (latency hides under softmax)
        uint2v m0k0r0, m0k0r1, m0k1r0, m0k1r1, m0k2r0, m0k2r1, m0k3r0, m0k3r1;
        uint2v m1k0r0, m1k0r1, m1k1r0, m1k1r1, m1k2r0, m1k2r1, m1k3r0, m1k3r1;
        TRR(m0k0r0, "0");    TRR(m0k0r1, "576");
        TRR(m0k1r0, "2048"); TRR(m0k1r1, "2624");
        TRR(m0k2r0, "4096"); TRR(m0k2r1, "4672");
        TRR(m0k3r0, "6144"); TRR(m0k3r1, "6720");
        TRR(m1k0r0, "64");   TRR(m1k0r1, "512");
        TRR(m1k1r0, "2112"); TRR(m1k1r1, "2560");
        TRR(m1k2r0, "4160"); TRR(m1k2r1, "4608");
        TRR(m1k3r0, "6208"); TRR(m1k3r1, "6656");

        // ---- softmax: v_max3 tree, defer-max check, exp (m==0 fast path), sum
        {
            float t0 = max3(s0[0],  s0[1],  s0[2]);
            float t1 = max3(s0[3],  s0[4],  s0[5]);
            float t2 = max3(s0[6],  s0[7],  s0[8]);
            float t3 = max3(s0[9],  s0[10], s0[11]);
            float t4 = max3(s0[12], s0[13], s0[14]);
            float t5 = max3(s0[15], s1[0],  s1[1]);
            float t6 = max3(s1[2],  s1[3],  s1[4]);
            float t7 = max3(s1[5],  s1[6],  s1[7]);
            float t8 = max3(s1[8],  s1[9],  s1[10]);
            float t9 = max3(s1[11], s1[12], s1[13]);
            float ta = fmaxf(s1[14], s1[15]);
            float u0 = max3(t0, t1, t2);
            float u1 = max3(t3, t4, t5);
            float u2 = max3(t6, t7, t8);
            float u3 = max3(t9, ta, u0);
            float pmax = max3(u1, u2, u3);
            pmax = fmaxf(pmax, other_half(pmax, hi));
            if (!__all(pmax - m_run <= 12.0f)) {    // T13: almost never taken
                float mn    = fmaxf(m_run, pmax);
                float alpha = exp2v(m_run - mn);
                m_run = mn;
                l_run *= alpha;
                #pragma unroll
                for (int r = 0; r < 16; ++r) { oacc0[r] *= alpha; oacc1[r] *= alpha; }
            }
        }
        if (__all(m_run == 0.0f)) {                 // fast path: no subtract
            #pragma unroll
            for (int r = 0; r < 16; ++r) s0[r] = exp2v(s0[r]);
            #pragma unroll
            for (int r = 0; r < 16; ++r) s1[r] = exp2v(s1[r]);
        } else {
            #pragma unroll
            for (int r = 0; r < 16; ++r) s0[r] = exp2v(s0[r] - m_run);
            #pragma unroll
            for (int r = 0; r < 16; ++r) s1[r] = exp2v(s1[r] - m_run);
        }
        {
            float a0 = SUM4(s0[0], s0[1], s0[2],  s0[3]);
            float a1 = SUM4(s0[4], s0[5], s0[6],  s0[7]);
            float a2 = SUM4(s0[8], s0[9], s0[10], s0[11]);
            float a3 = SUM4(s0[12], s0[13], s0[14], s0[15]);
            float b0 = SUM4(s1[0], s1[1], s1[2],  s1[3]);
            float b1 = SUM4(s1[4], s1[5], s1[6],  s1[7]);
            float b2 = SUM4(s1[8], s1[9], s1[10], s1[11]);
            float b3 = SUM4(s1[12], s1[13], s1[14], s1[15]);
            float rs = SUM4(SUM4(a0, a1, a2, a3), b0, b1, b2) + b3;
            rs += other_half(rs, hi);
            l_run += rs;
        }

        // ---- P^T B-frags via pk + permlane32_swap (T12)
        bf16x8 bfr0, bfr1, bfr2, bfr3;
        {
            uint2v x1 = __builtin_amdgcn_permlane32_swap(pk(s0[0], s0[1]),  pk(s0[4], s0[5]),  false, false);
            uint2v x2 = __builtin_amdgcn_permlane32_swap(pk(s0[2], s0[3]),  pk(s0[6], s0[7]),  false, false);
            uint4v w1 = { x1[0], x2[0], x1[1], x2[1] };
            bfr0 = __builtin_bit_cast(bf16x8, w1);
            uint2v y1 = __builtin_amdgcn_permlane32_swap(pk(s0[8], s0[9]),  pk(s0[12], s0[13]), false, false);
            uint2v y2 = __builtin_amdgcn_permlane32_swap(pk(s0[10], s0[11]), pk(s0[14], s0[15]), false, false);
            uint4v w2 = { y1[0], y2[0], y1[1], y2[1] };
            bfr1 = __builtin_bit_cast(bf16x8, w2);
            uint2v z1 = __builtin_amdgcn_permlane32_swap(pk(s1[0], s1[1]),  pk(s1[4], s1[5]),  false, false);
            uint2v z2 = __builtin_amdgcn_permlane32_swap(pk(s1[2], s1[3]),  pk(s1[6], s1[7]),  false, false);
            uint4v w3 = { z1[0], z2[0], z1[1], z2[1] };
            bfr2 = __builtin_bit_cast(bf16x8, w3);
            uint2v u1 = __builtin_amdgcn_permlane32_swap(pk(s1[8], s1[9]),  pk(s1[12], s1[13]), false, false);
            uint2v u2 = __builtin_amdgcn_permlane32_swap(pk(s1[10], s1[11]), pk(s1[14], s1[15]), false, false);
            uint4v w4 = { u1[0], u2[0], u1[1], u2[1] };
            bfr3 = __builtin_bit_cast(bf16x8, w4);
        }

        // ---- rule #18: drain DS (stage writes + tr_reads), fence, then PV MFMAs
        asm volatile("s_waitcnt lgkmcnt(0)" ::: "memory");
        __builtin_amdgcn_sched_barrier(0);

        __builtin_amdgcn_s_setprio(1);
        oacc0 = MFMA32(frag_of(m0k0r0, m0k0r1), bfr0, oacc0);
        oacc1 = MFMA32(frag_of(m1k0r0, m1k0r1), bfr0, oacc1);
        oacc0 = MFMA32(frag_of(m0k1r0, m0k1r1), bfr1, oacc0);
        oacc1 = MFMA32(frag_of(m1k1r0, m1k1r1), bfr1, oacc1);
        oacc0 = MFMA32(frag_of(m0k2r0, m0k2r1), bfr2, oacc0);
        oacc1 = MFMA32(frag_of(m1k2r0, m1k2r1), bfr2, oacc1);
        oacc0 = MFMA32(frag_of(m0k3r0, m0k3r1), bfr3, oacc0);
        oacc1 = MFMA32(frag_of(m1k3r0, m1k3r1), bfr3, oacc1);
        __builtin_amdgcn_s_setprio(0);

        // ---- issue tile+2 global loads (consumed after next barrier + QK^T)
        if (tile + 2 < NT) {
            const float* kp = kg + (size_t)(tile + 2) * KVBLK * DIM;
            const float* vp = vg + (size_t)(tile + 2) * KVBLK * DIM;
            #pragma unroll
            for (int i = 0; i < 4; ++i) {
                rk[i] = *(const float4*)(kp + i * 4);
                rv[i] = *(const float4*)(vp + i * 4);
            }
        }
    }

    // ---- epilogue: O^T regs (d = mblk*32 + crow(r,hi), q = l31), normalize, store
    float invl = 1.0f / l_run;
    float* op = out + bbase + (size_t)(q0w + l31) * DIM + 4 * hi;
    #pragma unroll
    for (int rq = 0; rq < 4; ++rq) {
        float4 o0 = { oacc0[4 * rq] * invl, oacc0[4 * rq + 1] * invl,
                      oacc0[4 * rq + 2] * invl, oacc0[4 * rq + 3] * invl };
        float4 o1 = { oacc1[4 * rq] * invl, oacc1[4 * rq + 1] * invl,
                      oacc1[4 * rq + 2] * invl, oacc1[4 * rq + 3] * invl };
        *(float4*)(op + 8 * rq)      = o0;
        *(float4*)(op + 32 + 8 * rq) = o1;
    }
}

extern "C" void kernel_launch(void* const* d_in, const int* in_sizes, int n_in,
                              void* d_out, int out_size, void* d_ws, size_t ws_size,
                              hipStream_t stream) {
    const float* q = (const float*)d_in[0];
    const float* k = (const float*)d_in[1];
    const float* v = (const float*)d_in[2];
    float* out = (float*)d_out;
    dim3 grid((SEQ / QBLK) * BATCH);   // 512
    dim3 block(256);
    hipLaunchKernelGGL(attn_fwd_kernel, grid, block, 0, stream, q, k, v, out);
}